// Round 1
// baseline (2398.816 us; speedup 1.0000x reference)
//
#include <hip/hip_runtime.h>
#include <hip/hip_bf16.h>
#include <math.h>

#define B_ 2
#define T_ 2048
#define D_ 1024
#define H_ 16
#define DH_ 64
#define M_ (B_*T_)   // 4096 rows

typedef __attribute__((ext_vector_type(4))) float floatx4;
typedef __attribute__((ext_vector_type(8))) short short8;

__device__ __forceinline__ ushort f2bf(float f) {
  union { float f; unsigned u; } c; c.f = f;
  unsigned r = (c.u + 0x7FFFu + ((c.u >> 16) & 1u)) >> 16;  // RNE
  return (ushort)r;
}
__device__ __forceinline__ float siluf(float u) {
  return u / (1.f + __expf(-u));
}
__device__ __forceinline__ float f4get(const float4& v, int j) {
  return j == 0 ? v.x : j == 1 ? v.y : j == 2 ? v.z : v.w;
}

// ---------- cast f32 -> bf16, n4 = n/4 ----------
__global__ void cast_kernel(const float* __restrict__ in, ushort* __restrict__ out, int n4) {
  int i = blockIdx.x * blockDim.x + threadIdx.x;
  if (i >= n4) return;
  float4 v = ((const float4*)in)[i];
  ushort4 o;
  o.x = f2bf(v.x); o.y = f2bf(v.y); o.z = f2bf(v.z); o.w = f2bf(v.w);
  ((ushort4*)out)[i] = o;
}

// ---------- transpose + cast: W[K][N] f32 -> Wt[N][K] bf16 ----------
__global__ void transpose_cast_kernel(const float* __restrict__ W, ushort* __restrict__ Wt,
                                      int K, int N) {
  __shared__ float tile[32][33];
  int tx = threadIdx.x, ty = threadIdx.y;
  int n0 = blockIdx.x * 32, k0 = blockIdx.y * 32;
  #pragma unroll
  for (int i = 0; i < 32; i += 8)
    tile[ty + i][tx] = W[(size_t)(k0 + ty + i) * N + n0 + tx];
  __syncthreads();
  #pragma unroll
  for (int i = 0; i < 32; i += 8)
    Wt[(size_t)(n0 + ty + i) * K + k0 + tx] = f2bf(tile[tx][ty + i]);
}

// ---------- bf16 MFMA GEMM: C[M][N] = A[M][K] * B[K][N], Bt is B transposed [N][K] ----------
// 64x64 C-tile per 256-thread block; wave w -> rows 16w..16w+15, 4 x (16x16) col tiles.
__global__ __launch_bounds__(256) void gemm_kernel(
    const ushort* __restrict__ A, const ushort* __restrict__ Bt,
    float* __restrict__ C, int M, int N, int K) {
  __shared__ short8 lds_a[64][5];   // [row][k-chunk of 8], 80B row stride (pad)
  __shared__ short8 lds_b[64][5];   // [col][k-chunk of 8]
  int tid = threadIdx.x;
  int wave = tid >> 6;
  int lane = tid & 63;
  int m16 = lane & 15;
  int q4  = lane >> 4;   // 0..3
  int bm = blockIdx.x, bn = blockIdx.y;
  floatx4 acc[4] = {};
  int sr  = tid >> 2;    // staging row 0..63
  int sc8 = tid & 3;     // staging short8 slot 0..3
  const short8* Arow = (const short8*)(A + (size_t)(bm * 64 + sr) * K) + sc8;
  const short8* Brow = (const short8*)(Bt + (size_t)(bn * 64 + sr) * K) + sc8;
  int nk8 = K >> 3;
  for (int k8 = 0; k8 < nk8; k8 += 4) {      // 32 k per iter
    short8 av = Arow[k8];
    short8 bv = Brow[k8];
    __syncthreads();
    lds_a[sr][sc8] = av;
    lds_b[sr][sc8] = bv;
    __syncthreads();
    short8 af = lds_a[wave * 16 + m16][q4];  // A[m=lane&15][k=(lane>>4)*8+j]
    #pragma unroll
    for (int tj = 0; tj < 4; tj++) {
      short8 bf = lds_b[tj * 16 + m16][q4];  // B[k][n=lane&15]
      acc[tj] = __builtin_amdgcn_mfma_f32_16x16x32_bf16(af, bf, acc[tj], 0, 0, 0);
    }
  }
  #pragma unroll
  for (int tj = 0; tj < 4; tj++) {
    #pragma unroll
    for (int i = 0; i < 4; i++) {
      int row = wave * 16 + q4 * 4 + i;      // C/D: row=(lane>>4)*4+reg
      int col = tj * 16 + m16;               //      col=lane&15
      C[(size_t)(bm * 64 + row) * N + bn * 64 + col] = acc[tj][i];
    }
  }
}

// ---------- beta = sigmoid(x @ Wb), Wb[D][H]; one block per row ----------
__global__ __launch_bounds__(256) void beta_kernel(const float* __restrict__ x,
                                                   const float* __restrict__ Wb,
                                                   float* __restrict__ beta) {
  __shared__ __align__(16) float xs[D_];
  int row = blockIdx.x;
  int tid = threadIdx.x;
  ((float4*)xs)[tid] = ((const float4*)(x + (size_t)row * D_))[tid];
  __syncthreads();
  int h = tid >> 4;      // 0..15
  int seg = tid & 15;    // 0..15 (16 segments of 64 over K)
  float s = 0.f;
  #pragma unroll 8
  for (int i = 0; i < 64; i++) {
    int kk = seg * 64 + i;
    s += xs[kk] * Wb[(size_t)kk * H_ + h];
  }
  #pragma unroll
  for (int off = 8; off; off >>= 1) s += __shfl_down(s, off, 16);
  if (seg == 0) beta[(size_t)row * H_ + h] = 1.f / (1.f + __expf(-s));
}

// ---------- causal depthwise conv(K=4) + silu, l2norm for q,k ----------
__global__ __launch_bounds__(256) void conv_kernel(
    const float* __restrict__ qpre, const float* __restrict__ kpre, const float* __restrict__ vpre,
    const float* __restrict__ cq, const float* __restrict__ ck, const float* __restrict__ cv,
    float* __restrict__ qo, float* __restrict__ ko, float* __restrict__ vo) {
  int row = blockIdx.x;          // b*T + t
  int t = row & (T_ - 1);
  int tid = threadIdx.x;
  int c0 = tid * 4;              // 4 channels per thread, head h = tid/16
  float4 zf = {0.f, 0.f, 0.f, 0.f};
  float4 xq[4], xk[4], xv[4];
  #pragma unroll
  for (int i = 0; i < 4; i++) {
    int tt = t - 3 + i;
    if (tt >= 0) {
      xq[i] = *(const float4*)(qpre + (size_t)(row - 3 + i) * D_ + c0);
      xk[i] = *(const float4*)(kpre + (size_t)(row - 3 + i) * D_ + c0);
      xv[i] = *(const float4*)(vpre + (size_t)(row - 3 + i) * D_ + c0);
    } else { xq[i] = zf; xk[i] = zf; xv[i] = zf; }
  }
  float yq[4], yk[4], yv[4];
  float pq = 0.f, pk = 0.f;
  #pragma unroll
  for (int j = 0; j < 4; j++) {
    float4 wq = ((const float4*)cq)[c0 + j];   // conv[c][0..3]
    float4 wk = ((const float4*)ck)[c0 + j];
    float4 wv = ((const float4*)cv)[c0 + j];
    float sq = 0.f, sk = 0.f, sv = 0.f;
    #pragma unroll
    for (int i = 0; i < 4; i++) {
      sq += f4get(wq, i) * f4get(xq[i], j);
      sk += f4get(wk, i) * f4get(xk[i], j);
      sv += f4get(wv, i) * f4get(xv[i], j);
    }
    yq[j] = siluf(sq); yk[j] = siluf(sk); yv[j] = siluf(sv);
    pq += yq[j] * yq[j]; pk += yk[j] * yk[j];
  }
  // l2norm over head (64 ch = 16 threads)
  #pragma unroll
  for (int off = 1; off < 16; off <<= 1) {
    pq += __shfl_xor(pq, off, 16);
    pk += __shfl_xor(pk, off, 16);
  }
  float rq = rsqrtf(pq + 1e-6f), rk = rsqrtf(pk + 1e-6f);
  float4 oq = {yq[0]*rq, yq[1]*rq, yq[2]*rq, yq[3]*rq};
  float4 okk = {yk[0]*rk, yk[1]*rk, yk[2]*rk, yk[3]*rk};
  float4 ov = {yv[0], yv[1], yv[2], yv[3]};
  *(float4*)(qo + (size_t)row * D_ + c0) = oq;
  *(float4*)(ko + (size_t)row * D_ + c0) = okk;
  *(float4*)(vo + (size_t)row * D_ + c0) = ov;
}

// ---------- delta-rule scan + per-head RMSNorm. One block per (b,h). ----------
// S[64][64] in registers: thread (ii=tid>>6, jj=tid&63) owns S[ii*16 .. ii*16+15][jj].
__global__ __launch_bounds__(256) void scan_kernel(
    const float* __restrict__ q, const float* __restrict__ k, const float* __restrict__ v,
    const float* __restrict__ beta, const float* __restrict__ rms_g,
    float* __restrict__ onorm) {
  int bh = blockIdx.x;
  int b = bh >> 4, h = bh & 15;
  int tid = threadIdx.x;
  int jj = tid & 63;
  int ii = tid >> 6;
  __shared__ __align__(16) float ks[64];
  __shared__ __align__(16) float qs[64];
  __shared__ __align__(16) float vs[64];
  __shared__ __align__(16) float us[64];
  __shared__ float part1[4][64];
  __shared__ float part2[4][64];
  __shared__ float beta_s;
  float S[16];
  #pragma unroll
  for (int i = 0; i < 16; i++) S[i] = 0.f;
  float g = rms_g[jj];
  const float* qb = q + (size_t)b * T_ * D_ + h * 64;
  const float* kb = k + (size_t)b * T_ * D_ + h * 64;
  const float* vb = v + (size_t)b * T_ * D_ + h * 64;
  const float* bb = beta + (size_t)b * T_ * H_ + h;
  for (int t = 0; t < T_; t++) {
    if (tid < 64)        ks[tid]       = kb[(size_t)t * D_ + tid];
    else if (tid < 128)  qs[tid - 64]  = qb[(size_t)t * D_ + (tid - 64)];
    else if (tid < 192)  vs[tid - 128] = vb[(size_t)t * D_ + (tid - 128)];
    else if (tid == 192) beta_s        = bb[(size_t)t * H_];
    __syncthreads();
    // phase A: partial kS over my 16 rows (k broadcast within wave: all lanes same ii)
    float4 k4[4], q4[4];
    #pragma unroll
    for (int r = 0; r < 4; r++) {
      k4[r] = *(const float4*)&ks[ii * 16 + r * 4];
      q4[r] = *(const float4*)&qs[ii * 16 + r * 4];
    }
    float p = 0.f;
    #pragma unroll
    for (int r = 0; r < 4; r++) {
      p += k4[r].x * S[r*4+0] + k4[r].y * S[r*4+1]
         + k4[r].z * S[r*4+2] + k4[r].w * S[r*4+3];
    }
    part1[ii][jj] = p;
    __syncthreads();
    // phase B: u = beta * (v - kS)
    if (tid < 64) {
      float kS = part1[0][jj] + part1[1][jj] + part1[2][jj] + part1[3][jj];
      us[jj] = beta_s * (vs[jj] - kS);
    }
    __syncthreads();
    // phase C: S += k u^T ; o partial = q^T S_new
    float u = us[jj];
    float o = 0.f;
    #pragma unroll
    for (int r = 0; r < 4; r++) {
      S[r*4+0] += k4[r].x * u;  o += q4[r].x * S[r*4+0];
      S[r*4+1] += k4[r].y * u;  o += q4[r].y * S[r*4+1];
      S[r*4+2] += k4[r].z * u;  o += q4[r].z * S[r*4+2];
      S[r*4+3] += k4[r].w * u;  o += q4[r].w * S[r*4+3];
    }
    part2[ii][jj] = o;
    __syncthreads();
    // phase D: reduce o, RMSNorm over the 64 dv components, store
    if (tid < 64) {
      float ov = part2[0][jj] + part2[1][jj] + part2[2][jj] + part2[3][jj];
      float ss = ov * ov;
      #pragma unroll
      for (int off = 32; off; off >>= 1) ss += __shfl_xor(ss, off, 64);
      float scale = rsqrtf(ss * (1.f / 64.f) + 1e-6f);
      onorm[((size_t)b * T_ + t) * D_ + h * 64 + jj] = ov * scale * g;
    }
  }
}

extern "C" void kernel_launch(void* const* d_in, const int* in_sizes, int n_in,
                              void* d_out, int out_size, void* d_ws, size_t ws_size,
                              hipStream_t stream) {
  const float* x  = (const float*)d_in[0];
  const float* Wq = (const float*)d_in[1];
  const float* Wk = (const float*)d_in[2];
  const float* Wv = (const float*)d_in[3];
  const float* Wb = (const float*)d_in[4];
  const float* cq = (const float*)d_in[5];
  const float* ck = (const float*)d_in[6];
  const float* cv = (const float*)d_in[7];
  const float* rg = (const float*)d_in[8];
  const float* Wo = (const float*)d_in[9];
  float* out = (float*)d_out;
  char* ws = (char*)d_ws;
  const size_t MiB = 1ull << 20;
  ushort* xb   = (ushort*)(ws + 0);        // 8 MiB
  ushort* Wqt  = (ushort*)(ws + 8 * MiB);  // 2 MiB each
  ushort* Wkt  = (ushort*)(ws + 10 * MiB);
  ushort* Wvt  = (ushort*)(ws + 12 * MiB);
  ushort* Wot  = (ushort*)(ws + 14 * MiB);
  float* qpre  = (float*)(ws + 16 * MiB);  // 16 MiB each
  float* kpre  = (float*)(ws + 32 * MiB);
  float* vpre  = (float*)(ws + 48 * MiB);
  float* qn    = (float*)(ws + 64 * MiB);
  float* kn    = (float*)(ws + 80 * MiB);
  float* vn    = (float*)(ws + 96 * MiB);
  float* beta  = (float*)(ws + 112 * MiB); // 256 KiB
  float* onorm = (float*)(ws + 16 * MiB);  // alias qpre (dead after conv)
  ushort* ob   = (ushort*)(ws + 32 * MiB); // alias kpre (dead after conv)

  hipLaunchKernelGGL(cast_kernel, dim3(M_ * D_ / 4 / 256), dim3(256), 0, stream,
                     x, xb, M_ * D_ / 4);
  dim3 tb(32, 8);
  hipLaunchKernelGGL(transpose_cast_kernel, dim3(32, 32), tb, 0, stream, Wq, Wqt, D_, D_);
  hipLaunchKernelGGL(transpose_cast_kernel, dim3(32, 32), tb, 0, stream, Wk, Wkt, D_, D_);
  hipLaunchKernelGGL(transpose_cast_kernel, dim3(32, 32), tb, 0, stream, Wv, Wvt, D_, D_);
  hipLaunchKernelGGL(transpose_cast_kernel, dim3(32, 32), tb, 0, stream, Wo, Wot, D_, D_);

  dim3 gg(M_ / 64, D_ / 64);
  hipLaunchKernelGGL(gemm_kernel, gg, dim3(256), 0, stream, xb, Wqt, qpre, M_, D_, D_);
  hipLaunchKernelGGL(gemm_kernel, gg, dim3(256), 0, stream, xb, Wkt, kpre, M_, D_, D_);
  hipLaunchKernelGGL(gemm_kernel, gg, dim3(256), 0, stream, xb, Wvt, vpre, M_, D_, D_);

  hipLaunchKernelGGL(beta_kernel, dim3(M_), dim3(256), 0, stream, x, Wb, beta);
  hipLaunchKernelGGL(conv_kernel, dim3(M_), dim3(256), 0, stream,
                     qpre, kpre, vpre, cq, ck, cv, qn, kn, vn);
  hipLaunchKernelGGL(scan_kernel, dim3(B_ * H_), dim3(256), 0, stream,
                     qn, kn, vn, beta, rg, onorm);
  hipLaunchKernelGGL(cast_kernel, dim3(M_ * D_ / 4 / 256), dim3(256), 0, stream,
                     onorm, ob, M_ * D_ / 4);
  hipLaunchKernelGGL(gemm_kernel, gg, dim3(256), 0, stream, ob, Wot, out, M_, D_, D_);
}

// Round 2
// 759.132 us; speedup vs baseline: 3.1599x; 3.1599x over previous
//
#include <hip/hip_runtime.h>
#include <hip/hip_bf16.h>
#include <math.h>

#define B_ 2
#define T_ 2048
#define D_ 1024
#define H_ 16
#define DH_ 64
#define M_ (B_*T_)   // 4096 rows
#define NC_ 32       // chunks per sequence (T/64)
#define CS_ 64       // chunk size
#define NCH_ (B_*H_*NC_)  // 1024 chunk-heads

typedef __attribute__((ext_vector_type(4))) float floatx4;
typedef __attribute__((ext_vector_type(8))) short short8;

__device__ __forceinline__ ushort f2bf(float f) {
  union { float f; unsigned u; } c; c.f = f;
  unsigned r = (c.u + 0x7FFFu + ((c.u >> 16) & 1u)) >> 16;  // RNE
  return (ushort)r;
}
__device__ __forceinline__ float siluf(float u) {
  return u / (1.f + __expf(-u));
}
__device__ __forceinline__ float f4get(const float4& v, int j) {
  return j == 0 ? v.x : j == 1 ? v.y : j == 2 ? v.z : v.w;
}

// ---------- cast f32 -> bf16, n4 = n/4 ----------
__global__ void cast_kernel(const float* __restrict__ in, ushort* __restrict__ out, int n4) {
  int i = blockIdx.x * blockDim.x + threadIdx.x;
  if (i >= n4) return;
  float4 v = ((const float4*)in)[i];
  ushort4 o;
  o.x = f2bf(v.x); o.y = f2bf(v.y); o.z = f2bf(v.z); o.w = f2bf(v.w);
  ((ushort4*)out)[i] = o;
}

// ---------- transpose + cast: W[K][N] f32 -> Wt[N][K] bf16 ----------
__global__ void transpose_cast_kernel(const float* __restrict__ W, ushort* __restrict__ Wt,
                                      int K, int N) {
  __shared__ float tile[32][33];
  int tx = threadIdx.x, ty = threadIdx.y;
  int n0 = blockIdx.x * 32, k0 = blockIdx.y * 32;
  #pragma unroll
  for (int i = 0; i < 32; i += 8)
    tile[ty + i][tx] = W[(size_t)(k0 + ty + i) * N + n0 + tx];
  __syncthreads();
  #pragma unroll
  for (int i = 0; i < 32; i += 8)
    Wt[(size_t)(n0 + ty + i) * K + k0 + tx] = f2bf(tile[tx][ty + i]);
}

// ---------- bf16 MFMA GEMM: C[M][N] = A[M][K] * B[K][N], Bt = B^T [N][K] ----------
__global__ __launch_bounds__(256) void gemm_kernel(
    const ushort* __restrict__ A, const ushort* __restrict__ Bt,
    float* __restrict__ C, int M, int N, int K) {
  __shared__ short8 lds_a[64][5];
  __shared__ short8 lds_b[64][5];
  int tid = threadIdx.x;
  int wave = tid >> 6;
  int lane = tid & 63;
  int m16 = lane & 15;
  int q4  = lane >> 4;
  int bm = blockIdx.x, bn = blockIdx.y;
  floatx4 acc[4] = {};
  int sr  = tid >> 2;
  int sc8 = tid & 3;
  const short8* Arow = (const short8*)(A + (size_t)(bm * 64 + sr) * K) + sc8;
  const short8* Brow = (const short8*)(Bt + (size_t)(bn * 64 + sr) * K) + sc8;
  int nk8 = K >> 3;
  for (int k8 = 0; k8 < nk8; k8 += 4) {
    short8 av = Arow[k8];
    short8 bv = Brow[k8];
    __syncthreads();
    lds_a[sr][sc8] = av;
    lds_b[sr][sc8] = bv;
    __syncthreads();
    short8 af = lds_a[wave * 16 + m16][q4];
    #pragma unroll
    for (int tj = 0; tj < 4; tj++) {
      short8 bf = lds_b[tj * 16 + m16][q4];
      acc[tj] = __builtin_amdgcn_mfma_f32_16x16x32_bf16(af, bf, acc[tj], 0, 0, 0);
    }
  }
  #pragma unroll
  for (int tj = 0; tj < 4; tj++) {
    #pragma unroll
    for (int i = 0; i < 4; i++) {
      int row = wave * 16 + q4 * 4 + i;
      int col = tj * 16 + m16;
      C[(size_t)(bm * 64 + row) * N + bn * 64 + col] = acc[tj][i];
    }
  }
}

// ---------- beta = sigmoid(x @ Wb) ----------
__global__ __launch_bounds__(256) void beta_kernel(const float* __restrict__ x,
                                                   const float* __restrict__ Wb,
                                                   float* __restrict__ beta) {
  __shared__ __align__(16) float xs[D_];
  int row = blockIdx.x;
  int tid = threadIdx.x;
  ((float4*)xs)[tid] = ((const float4*)(x + (size_t)row * D_))[tid];
  __syncthreads();
  int h = tid >> 4;
  int seg = tid & 15;
  float s = 0.f;
  #pragma unroll 8
  for (int i = 0; i < 64; i++) {
    int kk = seg * 64 + i;
    s += xs[kk] * Wb[(size_t)kk * H_ + h];
  }
  #pragma unroll
  for (int off = 8; off; off >>= 1) s += __shfl_down(s, off, 16);
  if (seg == 0) beta[(size_t)row * H_ + h] = 1.f / (1.f + __expf(-s));
}

// ---------- causal depthwise conv(K=4) + silu, l2norm for q,k ----------
__global__ __launch_bounds__(256) void conv_kernel(
    const float* __restrict__ qpre, const float* __restrict__ kpre, const float* __restrict__ vpre,
    const float* __restrict__ cq, const float* __restrict__ ck, const float* __restrict__ cv,
    float* __restrict__ qo, float* __restrict__ ko, float* __restrict__ vo) {
  int row = blockIdx.x;
  int t = row & (T_ - 1);
  int tid = threadIdx.x;
  int c0 = tid * 4;
  float4 zf = {0.f, 0.f, 0.f, 0.f};
  float4 xq[4], xk[4], xv[4];
  #pragma unroll
  for (int i = 0; i < 4; i++) {
    int tt = t - 3 + i;
    if (tt >= 0) {
      xq[i] = *(const float4*)(qpre + (size_t)(row - 3 + i) * D_ + c0);
      xk[i] = *(const float4*)(kpre + (size_t)(row - 3 + i) * D_ + c0);
      xv[i] = *(const float4*)(vpre + (size_t)(row - 3 + i) * D_ + c0);
    } else { xq[i] = zf; xk[i] = zf; xv[i] = zf; }
  }
  float yq[4], yk[4], yv[4];
  float pq = 0.f, pk = 0.f;
  #pragma unroll
  for (int j = 0; j < 4; j++) {
    float4 wq = ((const float4*)cq)[c0 + j];
    float4 wk = ((const float4*)ck)[c0 + j];
    float4 wv = ((const float4*)cv)[c0 + j];
    float sq = 0.f, sk = 0.f, sv = 0.f;
    #pragma unroll
    for (int i = 0; i < 4; i++) {
      sq += f4get(wq, i) * f4get(xq[i], j);
      sk += f4get(wk, i) * f4get(xk[i], j);
      sv += f4get(wv, i) * f4get(xv[i], j);
    }
    yq[j] = siluf(sq); yk[j] = siluf(sk); yv[j] = siluf(sv);
    pq += yq[j] * yq[j]; pk += yk[j] * yk[j];
  }
  #pragma unroll
  for (int off = 1; off < 16; off <<= 1) {
    pq += __shfl_xor(pq, off, 16);
    pk += __shfl_xor(pk, off, 16);
  }
  float rq = rsqrtf(pq + 1e-6f), rk = rsqrtf(pk + 1e-6f);
  float4 oq = {yq[0]*rq, yq[1]*rq, yq[2]*rq, yq[3]*rq};
  float4 okk = {yk[0]*rk, yk[1]*rk, yk[2]*rk, yk[3]*rk};
  float4 ov = {yv[0], yv[1], yv[2], yv[3]};
  *(float4*)(qo + (size_t)row * D_ + c0) = oq;
  *(float4*)(ko + (size_t)row * D_ + c0) = okk;
  *(float4*)(vo + (size_t)row * D_ + c0) = ov;
}

// ================= chunked delta rule =================
// prep1: per chunk-head, A = strict_tril(diag(b) K K^T); solve (I+A)Wk = diag(b)K,
//        (I+A)U0 = diag(b)V by right-looking forward substitution.
__global__ __launch_bounds__(256) void prep1_kernel(
    const float* __restrict__ kn, const float* __restrict__ vn,
    const float* __restrict__ beta,
    float* __restrict__ Wkbuf, float* __restrict__ U0buf) {
  __shared__ float Ksh[64][68];
  __shared__ float AT[64 * 64];   // AT[s][t] = A[t][s]
  __shared__ float Xs[64][68];
  __shared__ float bsh[64];
  int ch = blockIdx.x;
  int b = ch >> 9, h = (ch >> 5) & 15, c = ch & 31;
  int tid = threadIdx.x;
  int t = tid >> 2, seg = tid & 3;
  const float* krow = kn + ((size_t)(b * T_ + c * 64 + t)) * D_ + h * 64;
  #pragma unroll
  for (int g = 0; g < 4; g++)
    *(float4*)&Ksh[t][seg * 16 + 4 * g] = *(const float4*)&krow[seg * 16 + 4 * g];
  if (tid < 64) bsh[tid] = beta[((size_t)(b * T_ + c * 64 + tid)) * H_ + h];
  __syncthreads();
  {
    int s0 = seg * 16;
    float acc[16];
    #pragma unroll
    for (int r = 0; r < 16; r++) acc[r] = 0.f;
    for (int d4 = 0; d4 < 16; d4++) {
      float4 kt = *(float4*)&Ksh[t][d4 * 4];
      #pragma unroll
      for (int r = 0; r < 16; r++) {
        float4 ks = *(float4*)&Ksh[s0 + r][d4 * 4];
        acc[r] += kt.x * ks.x + kt.y * ks.y + kt.z * ks.z + kt.w * ks.w;
      }
    }
    float bt = bsh[t];
    #pragma unroll
    for (int r = 0; r < 16; r++) {
      int s = s0 + r;
      AT[s * 64 + t] = (t > s) ? bt * acc[r] : 0.f;
    }
  }
  __syncthreads();
  for (int pass = 0; pass < 2; pass++) {
    float bt = bsh[t];
    if (pass == 0) {
      #pragma unroll
      for (int g = 0; g < 4; g++) {
        float4 kv = *(float4*)&Ksh[t][seg * 16 + 4 * g];
        float4 xv = {bt * kv.x, bt * kv.y, bt * kv.z, bt * kv.w};
        *(float4*)&Xs[t][seg * 16 + 4 * g] = xv;
      }
    } else {
      const float* vrow = vn + ((size_t)(b * T_ + c * 64 + t)) * D_ + h * 64;
      #pragma unroll
      for (int g = 0; g < 4; g++) {
        float4 vv = *(const float4*)&vrow[seg * 16 + 4 * g];
        float4 xv = {bt * vv.x, bt * vv.y, bt * vv.z, bt * vv.w};
        *(float4*)&Xs[t][seg * 16 + 4 * g] = xv;
      }
    }
    __syncthreads();
    for (int i = 0; i < 63; i++) {
      if (t > i) {
        float a = AT[i * 64 + t];
        #pragma unroll
        for (int g = 0; g < 4; g++) {
          float4 xi = *(float4*)&Xs[i][seg * 16 + 4 * g];
          float4 xt = *(float4*)&Xs[t][seg * 16 + 4 * g];
          xt.x -= a * xi.x; xt.y -= a * xi.y; xt.z -= a * xi.z; xt.w -= a * xi.w;
          *(float4*)&Xs[t][seg * 16 + 4 * g] = xt;
        }
      }
      __syncthreads();
    }
    float* outb = (pass == 0) ? Wkbuf : U0buf;
    #pragma unroll
    for (int g = 0; g < 4; g++)
      *(float4*)&outb[(size_t)ch * 4096 + t * 64 + seg * 16 + 4 * g] =
          *(float4*)&Xs[t][seg * 16 + 4 * g];
    __syncthreads();
  }
}

// prep2a: L = tril(Q K^T) (incl diagonal)
__global__ __launch_bounds__(256) void prep2a_kernel(
    const float* __restrict__ qn, const float* __restrict__ kn,
    float* __restrict__ Lbuf) {
  __shared__ float Qsh[64][68];
  __shared__ float Ksh[64][68];
  int ch = blockIdx.x;
  int b = ch >> 9, h = (ch >> 5) & 15, c = ch & 31;
  int tid = threadIdx.x;
  int t = tid >> 2, seg = tid & 3;
  const float* qrow = qn + ((size_t)(b * T_ + c * 64 + t)) * D_ + h * 64;
  const float* krow = kn + ((size_t)(b * T_ + c * 64 + t)) * D_ + h * 64;
  #pragma unroll
  for (int g = 0; g < 4; g++) {
    *(float4*)&Qsh[t][seg * 16 + 4 * g] = *(const float4*)&qrow[seg * 16 + 4 * g];
    *(float4*)&Ksh[t][seg * 16 + 4 * g] = *(const float4*)&krow[seg * 16 + 4 * g];
  }
  __syncthreads();
  int s0 = seg * 16;
  float acc[16];
  #pragma unroll
  for (int r = 0; r < 16; r++) acc[r] = 0.f;
  for (int d4 = 0; d4 < 16; d4++) {
    float4 qt = *(float4*)&Qsh[t][d4 * 4];
    #pragma unroll
    for (int r = 0; r < 16; r++) {
      float4 ks = *(float4*)&Ksh[s0 + r][d4 * 4];
      acc[r] += qt.x * ks.x + qt.y * ks.y + qt.z * ks.z + qt.w * ks.w;
    }
  }
  #pragma unroll
  for (int g = 0; g < 4; g++) {
    float4 ov;
    ov.x = (s0 + 4*g + 0 <= t) ? acc[4*g+0] : 0.f;
    ov.y = (s0 + 4*g + 1 <= t) ? acc[4*g+1] : 0.f;
    ov.z = (s0 + 4*g + 2 <= t) ? acc[4*g+2] : 0.f;
    ov.w = (s0 + 4*g + 3 <= t) ? acc[4*g+3] : 0.f;
    *(float4*)&Lbuf[(size_t)ch * 4096 + t * 64 + s0 + 4 * g] = ov;
  }
}

// prep2b: O0 = L U0 ; Qeff = Q - L Wk (Qeff written in-place over qn)
__global__ __launch_bounds__(256) void prep2b_kernel(
    const float* __restrict__ Lbuf, const float* __restrict__ Wkbuf,
    const float* __restrict__ U0buf, float* qn,
    float* __restrict__ O0buf) {
  __shared__ float Lsh[64][68];
  __shared__ float Wksh[64][68];
  __shared__ float U0sh[64][68];
  int ch = blockIdx.x;
  int b = ch >> 9, h = (ch >> 5) & 15, c = ch & 31;
  int tid = threadIdx.x;
  int t = tid >> 2, seg = tid & 3;
  #pragma unroll
  for (int g = 0; g < 4; g++) {
    int o = t * 64 + seg * 16 + 4 * g;
    *(float4*)&Lsh[t][seg * 16 + 4 * g]  = *(const float4*)&Lbuf[(size_t)ch * 4096 + o];
    *(float4*)&Wksh[t][seg * 16 + 4 * g] = *(const float4*)&Wkbuf[(size_t)ch * 4096 + o];
    *(float4*)&U0sh[t][seg * 16 + 4 * g] = *(const float4*)&U0buf[(size_t)ch * 4096 + o];
  }
  __syncthreads();
  int j0 = seg * 16;
  float o0[16], lw[16];
  #pragma unroll
  for (int r = 0; r < 16; r++) { o0[r] = 0.f; lw[r] = 0.f; }
  for (int s = 0; s <= t; s++) {
    float l = Lsh[t][s];
    #pragma unroll
    for (int g = 0; g < 4; g++) {
      float4 u = *(float4*)&U0sh[s][j0 + 4 * g];
      float4 w = *(float4*)&Wksh[s][j0 + 4 * g];
      o0[4*g+0] += l * u.x; o0[4*g+1] += l * u.y; o0[4*g+2] += l * u.z; o0[4*g+3] += l * u.w;
      lw[4*g+0] += l * w.x; lw[4*g+1] += l * w.y; lw[4*g+2] += l * w.z; lw[4*g+3] += l * w.w;
    }
  }
  float* qrow = qn + ((size_t)(b * T_ + c * 64 + t)) * D_ + h * 64;
  #pragma unroll
  for (int g = 0; g < 4; g++) {
    float4 qv = *(const float4*)&qrow[j0 + 4 * g];
    qv.x -= lw[4*g+0]; qv.y -= lw[4*g+1]; qv.z -= lw[4*g+2]; qv.w -= lw[4*g+3];
    *(float4*)&qrow[j0 + 4 * g] = qv;
    float4 ov = {o0[4*g+0], o0[4*g+1], o0[4*g+2], o0[4*g+3]};
    *(float4*)&O0buf[(size_t)ch * 4096 + t * 64 + j0 + 4 * g] = ov;
  }
}

// prep2c: P = I - K^T Wk -> Pbuf; Z = K^T U0 -> written in-place over kn chunk
__global__ __launch_bounds__(256) void prep2c_kernel(
    float* kn, const float* __restrict__ Wkbuf,
    const float* __restrict__ U0buf, float* __restrict__ Pbuf) {
  __shared__ float Ksh[64][68];
  __shared__ float Wksh[64][68];
  __shared__ float U0sh[64][68];
  int ch = blockIdx.x;
  int b = ch >> 9, h = (ch >> 5) & 15, c = ch & 31;
  int tid = threadIdx.x;
  int t = tid >> 2, seg = tid & 3;
  const float* krow = kn + ((size_t)(b * T_ + c * 64 + t)) * D_ + h * 64;
  #pragma unroll
  for (int g = 0; g < 4; g++) {
    int o = t * 64 + seg * 16 + 4 * g;
    *(float4*)&Ksh[t][seg * 16 + 4 * g]  = *(const float4*)&krow[seg * 16 + 4 * g];
    *(float4*)&Wksh[t][seg * 16 + 4 * g] = *(const float4*)&Wkbuf[(size_t)ch * 4096 + o];
    *(float4*)&U0sh[t][seg * 16 + 4 * g] = *(const float4*)&U0buf[(size_t)ch * 4096 + o];
  }
  __syncthreads();
  int d = t;            // dk row
  int e0 = seg * 16;    // column block
  float accP[16], accZ[16];
  #pragma unroll
  for (int r = 0; r < 16; r++) { accP[r] = 0.f; accZ[r] = 0.f; }
  for (int s = 0; s < 64; s++) {
    float kv = Ksh[s][d];
    #pragma unroll
    for (int g = 0; g < 4; g++) {
      float4 w = *(float4*)&Wksh[s][e0 + 4 * g];
      float4 u = *(float4*)&U0sh[s][e0 + 4 * g];
      accP[4*g+0] += kv * w.x; accP[4*g+1] += kv * w.y; accP[4*g+2] += kv * w.z; accP[4*g+3] += kv * w.w;
      accZ[4*g+0] += kv * u.x; accZ[4*g+1] += kv * u.y; accZ[4*g+2] += kv * u.z; accZ[4*g+3] += kv * u.w;
    }
  }
  float* zrow = kn + ((size_t)(b * T_ + c * 64 + d)) * D_ + h * 64;
  #pragma unroll
  for (int g = 0; g < 4; g++) {
    float4 pv;
    pv.x = ((e0 + 4*g + 0) == d ? 1.f : 0.f) - accP[4*g+0];
    pv.y = ((e0 + 4*g + 1) == d ? 1.f : 0.f) - accP[4*g+1];
    pv.z = ((e0 + 4*g + 2) == d ? 1.f : 0.f) - accP[4*g+2];
    pv.w = ((e0 + 4*g + 3) == d ? 1.f : 0.f) - accP[4*g+3];
    *(float4*)&Pbuf[(size_t)ch * 4096 + d * 64 + e0 + 4 * g] = pv;
    float4 zv = {accZ[4*g+0], accZ[4*g+1], accZ[4*g+2], accZ[4*g+3]};
    *(float4*)&zrow[e0 + 4 * g] = zv;
  }
}

// chunk scan: per (b,h,js): sequential over 32 chunks: O = O0 + Qeff*S ; S = P*S + Z
__global__ __launch_bounds__(256) void chunk_scan_kernel(
    const float* __restrict__ qn /*Qeff*/, const float* __restrict__ kn /*Z*/,
    const float* __restrict__ Pbuf, float* Obuf /*O0 in, O out*/) {
  __shared__ float Qs[64][68];
  __shared__ float Ps[64][68];
  __shared__ float ST[2][16][68];
  int bid = blockIdx.x;
  int js = bid & 3, h = (bid >> 2) & 15, b = bid >> 6;
  int tid = threadIdx.x;
  int t4 = tid >> 2, seg = tid & 3;
  for (int i = tid; i < 2 * 16 * 68; i += 256) ((float*)ST)[i] = 0.f;
  __syncthreads();
  int cur = 0;
  int jj = tid & 15, tq = tid >> 4;
  for (int c = 0; c < NC_; c++) {
    int ch = ((b * H_ + h) * NC_ + c);
    const float* qrow = qn + ((size_t)(b * T_ + c * 64 + t4)) * D_ + h * 64;
    #pragma unroll
    for (int g = 0; g < 4; g++) {
      *(float4*)&Qs[t4][seg * 16 + 4 * g] = *(const float4*)&qrow[seg * 16 + 4 * g];
      *(float4*)&Ps[t4][seg * 16 + 4 * g] =
          *(const float4*)&Pbuf[(size_t)ch * 4096 + t4 * 64 + seg * 16 + 4 * g];
    }
    __syncthreads();
    // O phase (uses S before update)
    float o[4];
    #pragma unroll
    for (int r = 0; r < 4; r++)
      o[r] = Obuf[(size_t)ch * 4096 + (tq * 4 + r) * 64 + js * 16 + jj];
    for (int d4 = 0; d4 < 16; d4++) {
      float4 s4 = *(float4*)&ST[cur][jj][d4 * 4];
      #pragma unroll
      for (int r = 0; r < 4; r++) {
        float4 q4 = *(float4*)&Qs[tq * 4 + r][d4 * 4];
        o[r] += q4.x * s4.x + q4.y * s4.y + q4.z * s4.z + q4.w * s4.w;
      }
    }
    #pragma unroll
    for (int r = 0; r < 4; r++)
      Obuf[(size_t)ch * 4096 + (tq * 4 + r) * 64 + js * 16 + jj] = o[r];
    // S update: Snew[d][jj] = Z[d][jj] + sum_e P[d][e]*S[e][jj]
    float sn[4];
    #pragma unroll
    for (int r = 0; r < 4; r++)
      sn[r] = kn[((size_t)(b * T_ + c * 64 + (tq * 4 + r))) * D_ + h * 64 + js * 16 + jj];
    for (int e4 = 0; e4 < 16; e4++) {
      float4 s4 = *(float4*)&ST[cur][jj][e4 * 4];
      #pragma unroll
      for (int r = 0; r < 4; r++) {
        float4 p4 = *(float4*)&Ps[tq * 4 + r][e4 * 4];
        sn[r] += p4.x * s4.x + p4.y * s4.y + p4.z * s4.z + p4.w * s4.w;
      }
    }
    #pragma unroll
    for (int r = 0; r < 4; r++)
      ST[cur ^ 1][jj][tq * 4 + r] = sn[r];
    __syncthreads();
    cur ^= 1;
  }
}

// per-head RMSNorm + cast to bf16, chunk layout -> [B,T,D]
__global__ __launch_bounds__(256) void rmsnorm_cast_kernel(
    const float* __restrict__ Obuf, const float* __restrict__ rms_g,
    ushort* __restrict__ ob) {
  int row = blockIdx.x;
  int b = row >> 11, t = row & (T_ - 1);
  int c = t >> 6, tl = t & 63;
  int tid = threadIdx.x;
  int h = tid >> 4, l16 = tid & 15;
  int ch = ((b * H_ + h) * NC_ + c);
  float4 o = *(const float4*)&Obuf[(size_t)ch * 4096 + tl * 64 + l16 * 4];
  float ss = o.x * o.x + o.y * o.y + o.z * o.z + o.w * o.w;
  #pragma unroll
  for (int off = 8; off; off >>= 1) ss += __shfl_xor(ss, off, 16);
  float sc = rsqrtf(ss * (1.f / 64.f) + 1e-6f);
  float4 g4 = *(const float4*)&rms_g[l16 * 4];
  ushort4 r;
  r.x = f2bf(o.x * sc * g4.x); r.y = f2bf(o.y * sc * g4.y);
  r.z = f2bf(o.z * sc * g4.z); r.w = f2bf(o.w * sc * g4.w);
  *(ushort4*)&ob[(size_t)row * D_ + tid * 4] = r;
}

extern "C" void kernel_launch(void* const* d_in, const int* in_sizes, int n_in,
                              void* d_out, int out_size, void* d_ws, size_t ws_size,
                              hipStream_t stream) {
  const float* x  = (const float*)d_in[0];
  const float* Wq = (const float*)d_in[1];
  const float* Wk = (const float*)d_in[2];
  const float* Wv = (const float*)d_in[3];
  const float* Wb = (const float*)d_in[4];
  const float* cq = (const float*)d_in[5];
  const float* ck = (const float*)d_in[6];
  const float* cv = (const float*)d_in[7];
  const float* rg = (const float*)d_in[8];
  const float* Wo = (const float*)d_in[9];
  float* out = (float*)d_out;
  char* ws = (char*)d_ws;
  const size_t MiB = 1ull << 20;
  // Layout (max 112.25 MiB):
  ushort* xb   = (ushort*)(ws + 0);         // 8 MiB, dead after QKV gemms
  ushort* Wqt  = (ushort*)(ws + 8 * MiB);
  ushort* Wkt  = (ushort*)(ws + 10 * MiB);
  ushort* Wvt  = (ushort*)(ws + 12 * MiB);
  ushort* Wot  = (ushort*)(ws + 14 * MiB);  // live to end
  float* qpre  = (float*)(ws + 16 * MiB);   // dead after conv
  float* kpre  = (float*)(ws + 32 * MiB);
  float* vpre  = (float*)(ws + 48 * MiB);
  float* qn    = (float*)(ws + 64 * MiB);   // then Qeff in-place
  float* kn    = (float*)(ws + 80 * MiB);   // then Z in-place
  float* vn    = (float*)(ws + 96 * MiB);   // dead after prep1
  float* beta  = (float*)(ws + 112 * MiB);  // 256 KiB
  float* Wkbuf = (float*)(ws + 16 * MiB);   // over qpre
  float* U0buf = (float*)(ws + 32 * MiB);   // over kpre
  float* Lbuf  = (float*)(ws + 48 * MiB);   // over vpre; later P
  float* O0buf = (float*)(ws + 96 * MiB);   // over vn (after prep1)
  ushort* ob   = (ushort*)(ws + 0);         // over xb (after gemms)

  hipLaunchKernelGGL(cast_kernel, dim3(M_ * D_ / 4 / 256), dim3(256), 0, stream,
                     x, xb, M_ * D_ / 4);
  dim3 tb(32, 8);
  hipLaunchKernelGGL(transpose_cast_kernel, dim3(32, 32), tb, 0, stream, Wq, Wqt, D_, D_);
  hipLaunchKernelGGL(transpose_cast_kernel, dim3(32, 32), tb, 0, stream, Wk, Wkt, D_, D_);
  hipLaunchKernelGGL(transpose_cast_kernel, dim3(32, 32), tb, 0, stream, Wv, Wvt, D_, D_);
  hipLaunchKernelGGL(transpose_cast_kernel, dim3(32, 32), tb, 0, stream, Wo, Wot, D_, D_);

  dim3 gg(M_ / 64, D_ / 64);
  hipLaunchKernelGGL(gemm_kernel, gg, dim3(256), 0, stream, xb, Wqt, qpre, M_, D_, D_);
  hipLaunchKernelGGL(gemm_kernel, gg, dim3(256), 0, stream, xb, Wkt, kpre, M_, D_, D_);
  hipLaunchKernelGGL(gemm_kernel, gg, dim3(256), 0, stream, xb, Wvt, vpre, M_, D_, D_);

  hipLaunchKernelGGL(beta_kernel, dim3(M_), dim3(256), 0, stream, x, Wb, beta);
  hipLaunchKernelGGL(conv_kernel, dim3(M_), dim3(256), 0, stream,
                     qpre, kpre, vpre, cq, ck, cv, qn, kn, vn);

  hipLaunchKernelGGL(prep1_kernel, dim3(NCH_), dim3(256), 0, stream,
                     kn, vn, beta, Wkbuf, U0buf);
  hipLaunchKernelGGL(prep2a_kernel, dim3(NCH_), dim3(256), 0, stream, qn, kn, Lbuf);
  hipLaunchKernelGGL(prep2b_kernel, dim3(NCH_), dim3(256), 0, stream,
                     Lbuf, Wkbuf, U0buf, qn, O0buf);
  hipLaunchKernelGGL(prep2c_kernel, dim3(NCH_), dim3(256), 0, stream,
                     kn, Wkbuf, U0buf, Lbuf);
  hipLaunchKernelGGL(chunk_scan_kernel, dim3(B_ * H_ * 4), dim3(256), 0, stream,
                     qn, kn, Lbuf, O0buf);
  hipLaunchKernelGGL(rmsnorm_cast_kernel, dim3(M_), dim3(256), 0, stream,
                     O0buf, rg, ob);
  hipLaunchKernelGGL(gemm_kernel, gg, dim3(256), 0, stream, ob, Wot, out, M_, D_, D_);
}